// Round 3
// baseline (930.044 us; speedup 1.0000x reference)
//
#include <hip/hip_runtime.h>

#define N_NODES 50000
#define N_EDGES 1600000
#define D_FEAT 32

#define NODES_PER_BUCKET 64
#define N_BUCKETS ((N_NODES + NODES_PER_BUCKET - 1) / NODES_PER_BUCKET)  // 782
#define CAP8 2432   // mean 2048, sigma ~45 -> +8.5 sigma headroom
#define CAP4 2304
#define ACC_STRIDE 33  // 64-node x 32-feat accumulator, +1 padding vs 32 banks

// ws layout: [0,4096) bucket cursors (ints); [4096, ...) pair buffer.

// Pass A (wide): append (packed, src) per edge into its dst-bucket stream.
// packed = (eid << 6) | (dst & 63); bucket = dst >> 6.
__global__ void bin_edges_8(const int* __restrict__ src,
                            const int* __restrict__ dst,
                            int* __restrict__ bcur,
                            int2* __restrict__ pairs) {
    int e = blockIdx.x * blockDim.x + threadIdx.x;
    if (e >= N_EDGES) return;
    int d = dst[e];
    int b = d >> 6;
    int pos = atomicAdd(&bcur[b], 1);
    if (pos < CAP8)
        pairs[(size_t)b * CAP8 + pos] = make_int2((e << 6) | (d & 63), src[e]);
}

// Pass A (narrow fallback): packed only; src re-read in pass B.
__global__ void bin_edges_4(const int* __restrict__ dst,
                            int* __restrict__ bcur,
                            int* __restrict__ pairs) {
    int e = blockIdx.x * blockDim.x + threadIdx.x;
    if (e >= N_EDGES) return;
    int d = dst[e];
    int b = d >> 6;
    int pos = atomicAdd(&bcur[b], 1);
    if (pos < CAP4)
        pairs[(size_t)b * CAP4 + pos] = (e << 6) | (d & 63);
}

// Pass B: one workgroup per bucket. LDS accumulator 64 nodes x 32 feats
// (stride 33). 8 lanes per pair: lane g owns float4 feature group g.
template <int STORED_SRC>
__global__ void bucket_aggregate(const float* __restrict__ node_feat,
                                 const float* __restrict__ edge_feat,
                                 const float* __restrict__ eps,
                                 const int* __restrict__ src,
                                 const int* __restrict__ bcur,
                                 const int2* __restrict__ pairs8,
                                 const int* __restrict__ pairs4,
                                 float* __restrict__ out) {
    __shared__ float acc[NODES_PER_BUCKET * ACC_STRIDE];  // 8448 B

    int b = blockIdx.x;
    int tid = threadIdx.x;
    int base_node = b * NODES_PER_BUCKET;
    int nn = N_NODES - base_node;
    if (nn > NODES_PER_BUCKET) nn = NODES_PER_BUCKET;

    for (int i = tid; i < NODES_PER_BUCKET * ACC_STRIDE; i += blockDim.x)
        acc[i] = 0.0f;
    __syncthreads();

    int cnt = bcur[b];
    int cap = STORED_SRC ? CAP8 : CAP4;
    if (cnt > cap) cnt = cap;

    int sub = tid >> 3;   // 0..31 pair slot
    int g   = tid & 7;    // float4 group within 32 feats

    for (int p = sub; p < cnt; p += 32) {
        int packed, s;
        if (STORED_SRC) {
            int2 pr = pairs8[(size_t)b * CAP8 + p];
            packed = pr.x;
            s = pr.y;
        } else {
            packed = pairs4[(size_t)b * CAP4 + p];
            s = src[packed >> 6];
        }
        int eid = packed >> 6;
        int ln  = packed & 63;

        float4 ef = ((const float4*)edge_feat)[(size_t)eid * 8 + g];
        float4 nf = ((const float4*)node_feat)[s * 8 + g];

        float* a = &acc[ln * ACC_STRIDE + g * 4];
        atomicAdd(a + 0, fmaxf(nf.x + ef.x, 0.0f));
        atomicAdd(a + 1, fmaxf(nf.y + ef.y, 0.0f));
        atomicAdd(a + 2, fmaxf(nf.z + ef.z, 0.0f));
        atomicAdd(a + 3, fmaxf(nf.w + ef.w, 0.0f));
    }
    __syncthreads();

    float scale = 1.0f + eps[0];
    for (int i = tid; i < nn * 8; i += blockDim.x) {
        int ln = i >> 3;
        int gg = i & 7;
        int node = base_node + ln;
        float4 h = ((const float4*)node_feat)[node * 8 + gg];
        const float* a = &acc[ln * ACC_STRIDE + gg * 4];
        float4 o;
        o.x = scale * h.x + a[0];
        o.y = scale * h.y + a[1];
        o.z = scale * h.z + a[2];
        o.w = scale * h.w + a[3];
        ((float4*)out)[node * 8 + gg] = o;
    }
}

extern "C" void kernel_launch(void* const* d_in, const int* in_sizes, int n_in,
                              void* d_out, int out_size, void* d_ws, size_t ws_size,
                              hipStream_t stream) {
    const float* node_feat = (const float*)d_in[0];
    const float* edge_feat = (const float*)d_in[1];
    const float* eps       = (const float*)d_in[2];
    const int*   src       = (const int*)d_in[3];
    const int*   dst       = (const int*)d_in[4];
    float* out = (float*)d_out;

    int* bcur = (int*)d_ws;
    void* pbuf = (char*)d_ws + 4096;

    const size_t need8 = 4096 + (size_t)N_BUCKETS * CAP8 * sizeof(int2);
    bool big = ws_size >= need8;

    hipMemsetAsync(d_ws, 0, 1024 * sizeof(int), stream);

    const int B = 256;
    int gridA = (N_EDGES + B - 1) / B;
    if (big) {
        bin_edges_8<<<gridA, B, 0, stream>>>(src, dst, bcur, (int2*)pbuf);
        bucket_aggregate<1><<<N_BUCKETS, B, 0, stream>>>(
            node_feat, edge_feat, eps, src, bcur, (const int2*)pbuf, nullptr, out);
    } else {
        bin_edges_4<<<gridA, B, 0, stream>>>(dst, bcur, (int*)pbuf);
        bucket_aggregate<0><<<N_BUCKETS, B, 0, stream>>>(
            node_feat, edge_feat, eps, src, bcur, nullptr, (const int*)pbuf, out);
    }
}

// Round 4
// 508.564 us; speedup vs baseline: 1.8288x; 1.8288x over previous
//
#include <hip/hip_runtime.h>

#define N_NODES 50000
#define N_EDGES 1600000
#define D_FEAT 32
#define SCAN_BLOCK 1024
#define N_SCAN_BLOCKS ((N_NODES + SCAN_BLOCK - 1) / SCAN_BLOCK)  // 49

// ws layout (int units):
//   cnt   [0, N)       per-dst edge count (histogram)
//   excl  [N, 2N)      per-block exclusive scan of cnt
//   off   [2N, 3N)     global exclusive offsets
//   bsum  [3N, 3N+64)
//   bsumx [3N+64, 3N+128)
//   rank  [3N+128, 3N+128+E)   rank of edge within its dst bin (coalesced)
//   msg   [3N+128+E, ...)      float: E x 32 sorted messages (204.8 MB)
#define WS_CNT   0
#define WS_EXCL  (N_NODES)
#define WS_OFF   (2 * N_NODES)
#define WS_BSUM  (3 * N_NODES)
#define WS_BSUMX (3 * N_NODES + 64)
#define WS_RANK  (3 * N_NODES + 128)
#define WS_MSG   (3 * N_NODES + 128 + N_EDGES)

// -------- main path --------

// rank[e] = old count of dst[e]; cnt accumulates histogram. rank write coalesced.
__global__ void hist_rank(const int* __restrict__ dst,
                          int* __restrict__ cnt,
                          int* __restrict__ rank) {
    int e = blockIdx.x * blockDim.x + threadIdx.x;
    if (e < N_EDGES) rank[e] = atomicAdd(&cnt[dst[e]], 1);
}

__global__ void scan_blocks(const int* __restrict__ cnt,
                            int* __restrict__ excl,
                            int* __restrict__ bsum) {
    __shared__ int lds[SCAN_BLOCK];
    int tid = threadIdx.x;
    int i = blockIdx.x * SCAN_BLOCK + tid;
    int v = (i < N_NODES) ? cnt[i] : 0;
    int sum = v;
    lds[tid] = v;
    __syncthreads();
    for (int ofs = 1; ofs < SCAN_BLOCK; ofs <<= 1) {
        int t = (tid >= ofs) ? lds[tid - ofs] : 0;
        __syncthreads();
        sum += t;
        lds[tid] = sum;
        __syncthreads();
    }
    if (i < N_NODES) excl[i] = sum - v;
    if (tid == SCAN_BLOCK - 1) bsum[blockIdx.x] = lds[SCAN_BLOCK - 1];
}

// one wave: shuffle-based exclusive scan of the 49 block sums
__global__ void scan_bsums(const int* __restrict__ bsum, int* __restrict__ bsumx) {
    int lane = threadIdx.x;
    int orig = (lane < N_SCAN_BLOCKS) ? bsum[lane] : 0;
    int v = orig;
    for (int o = 1; o < 64; o <<= 1) {
        int t = __shfl_up(v, o);
        if (lane >= o) v += t;
    }
    if (lane < N_SCAN_BLOCKS) bsumx[lane] = v - orig;
}

__global__ void finalize_off(const int* __restrict__ excl,
                             const int* __restrict__ bsumx,
                             int* __restrict__ off) {
    int i = blockIdx.x * SCAN_BLOCK + threadIdx.x;
    if (i < N_NODES) off[i] = excl[i] + bsumx[blockIdx.x];
}

// 8 lanes per edge: compute relu(nf[src]+ef) and write the full 128B message
// row to its dst-sorted slot. Random address but full-sector -> no write amp.
__global__ void build_msg(const float* __restrict__ node_feat,
                          const float* __restrict__ edge_feat,
                          const int* __restrict__ src,
                          const int* __restrict__ dst,
                          const int* __restrict__ off,
                          const int* __restrict__ rank,
                          float* __restrict__ msg) {
    int t = blockIdx.x * blockDim.x + threadIdx.x;
    int e = t >> 3;
    int g = t & 7;
    if (e >= N_EDGES) return;

    int d = dst[e];
    int pos = off[d] + rank[e];
    int s = src[e];

    float4 ef = ((const float4*)edge_feat)[(size_t)e * 8 + g];
    float4 nf = ((const float4*)node_feat)[s * 8 + g];
    float4 m;
    m.x = fmaxf(nf.x + ef.x, 0.f);
    m.y = fmaxf(nf.y + ef.y, 0.f);
    m.z = fmaxf(nf.z + ef.z, 0.f);
    m.w = fmaxf(nf.w + ef.w, 0.f);
    ((float4*)msg)[(size_t)pos * 8 + g] = m;
}

// per (node, float4-group): sum the node's contiguous message rows + residual.
__global__ void reduce_msgs(const float* __restrict__ node_feat,
                            const float* __restrict__ eps,
                            const int* __restrict__ off,
                            const int* __restrict__ cnt,
                            const float* __restrict__ msg,
                            float* __restrict__ out) {
    int t = blockIdx.x * blockDim.x + threadIdx.x;
    int n = t >> 3;
    int g = t & 7;
    if (n >= N_NODES) return;

    int start = off[n];
    int c = cnt[n];

    float4 acc = make_float4(0.f, 0.f, 0.f, 0.f);
    for (int i = 0; i < c; ++i) {
        float4 m = ((const float4*)msg)[(size_t)(start + i) * 8 + g];
        acc.x += m.x; acc.y += m.y; acc.z += m.z; acc.w += m.w;
    }

    float scale = 1.0f + eps[0];
    float4 h = ((const float4*)node_feat)[n * 8 + g];
    float4 o;
    o.x = scale * h.x + acc.x;
    o.y = scale * h.y + acc.y;
    o.z = scale * h.z + acc.z;
    o.w = scale * h.w + acc.w;
    ((float4*)out)[n * 8 + g] = o;
}

// -------- fallback path (tiny ws): R0 direct atomics --------

__global__ void fb_init_out(const float* __restrict__ node_feat,
                            const float* __restrict__ eps,
                            float* __restrict__ out) {
    int i = blockIdx.x * blockDim.x + threadIdx.x;
    const int n4 = N_NODES * D_FEAT / 4;
    float scale = 1.0f + eps[0];
    if (i < n4) {
        float4 v = ((const float4*)node_feat)[i];
        v.x *= scale; v.y *= scale; v.z *= scale; v.w *= scale;
        ((float4*)out)[i] = v;
    }
}

__global__ void fb_scatter(const float* __restrict__ node_feat,
                           const float* __restrict__ edge_feat,
                           const int* __restrict__ src,
                           const int* __restrict__ dst,
                           float* __restrict__ out) {
    int t = blockIdx.x * blockDim.x + threadIdx.x;
    int e = t >> 3;
    int g = t & 7;
    if (e >= N_EDGES) return;
    int s = src[e];
    int d = dst[e];
    float4 nf = ((const float4*)node_feat)[s * 8 + g];
    float4 ef = ((const float4*)edge_feat)[(size_t)e * 8 + g];
    float* op = out + (size_t)d * D_FEAT + g * 4;
    unsafeAtomicAdd(op + 0, fmaxf(nf.x + ef.x, 0.f));
    unsafeAtomicAdd(op + 1, fmaxf(nf.y + ef.y, 0.f));
    unsafeAtomicAdd(op + 2, fmaxf(nf.z + ef.z, 0.f));
    unsafeAtomicAdd(op + 3, fmaxf(nf.w + ef.w, 0.f));
}

extern "C" void kernel_launch(void* const* d_in, const int* in_sizes, int n_in,
                              void* d_out, int out_size, void* d_ws, size_t ws_size,
                              hipStream_t stream) {
    const float* node_feat = (const float*)d_in[0];
    const float* edge_feat = (const float*)d_in[1];
    const float* eps       = (const float*)d_in[2];
    const int*   src       = (const int*)d_in[3];
    const int*   dst       = (const int*)d_in[4];
    float* out = (float*)d_out;

    const int B = 256;
    const size_t need = ((size_t)WS_MSG + (size_t)N_EDGES * D_FEAT) * sizeof(int);

    if (ws_size < need) {
        // fallback: direct fp32 atomics (no ws)
        int n4 = N_NODES * D_FEAT / 4;
        fb_init_out<<<(n4 + B - 1) / B, B, 0, stream>>>(node_feat, eps, out);
        long long total = (long long)N_EDGES * 8;
        fb_scatter<<<(int)((total + B - 1) / B), B, 0, stream>>>(
            node_feat, edge_feat, src, dst, out);
        return;
    }

    int* ws = (int*)d_ws;
    int*   cnt   = ws + WS_CNT;
    int*   excl  = ws + WS_EXCL;
    int*   off   = ws + WS_OFF;
    int*   bsum  = ws + WS_BSUM;
    int*   bsumx = ws + WS_BSUMX;
    int*   rank  = ws + WS_RANK;
    float* msg   = (float*)(ws + WS_MSG);

    hipMemsetAsync(cnt, 0, N_NODES * sizeof(int), stream);

    hist_rank<<<(N_EDGES + B - 1) / B, B, 0, stream>>>(dst, cnt, rank);
    scan_blocks<<<N_SCAN_BLOCKS, SCAN_BLOCK, 0, stream>>>(cnt, excl, bsum);
    scan_bsums<<<1, 64, 0, stream>>>(bsum, bsumx);
    finalize_off<<<N_SCAN_BLOCKS, SCAN_BLOCK, 0, stream>>>(excl, bsumx, off);

    long long etotal = (long long)N_EDGES * 8;
    build_msg<<<(int)((etotal + B - 1) / B), B, 0, stream>>>(
        node_feat, edge_feat, src, dst, off, rank, msg);

    long long ntotal = (long long)N_NODES * 8;
    reduce_msgs<<<(int)((ntotal + B - 1) / B), B, 0, stream>>>(
        node_feat, eps, off, cnt, msg, out);
}